// Round 10
// baseline (32.666 us; speedup 1.0000x reference)
//
#include <hip/hip_runtime.h>

#define HW    3136   // 56*56
#define HP2   1568   // HW/2 hw-pairs
#define KK    196
#define BCN   256    // B*C
#define KT    7      // k's per main block
#define NKC   28     // KK / KT
#define NSEG  49     // hw segments of 64 hw (32 pairs)
#define SPP   32     // hw-pairs per segment
#define LOG2E 1.4426950408889634f
// Schraudolph prescale folded into rf: rf' = rf * log2(e) * 2^23
#define PRESCALE (1.4426950408889634f * 8388608.0f)
// centered Schraudolph bias: 127*2^23 - 299487  (max rel err ~ +/-3.6%, zero-mean)
#define SCH_BIAS 1065053729.0f

typedef float v2f __attribute__((ext_vector_type(2)));

// ---- Kernel 1: repack rfs[hw][k] -> rfsP[kc][hp][j] = (rf[2hp][k], rf[2hp+1][k]) * PRESCALE.
__global__ __launch_bounds__(256) void rf_repack(const float* __restrict__ rfs,
                                                 v2f* __restrict__ rfsP) {
    const int idx = blockIdx.x * 256 + threadIdx.x;   // kc*HP2 + hpg
    if (idx < NKC * HP2) {
        const int kc  = idx / HP2;
        const int hpg = idx % HP2;
        const float* s0 = rfs + (size_t)(2 * hpg) * KK + kc * KT;
        v2f* d = rfsP + (size_t)idx * KT;
        #pragma unroll
        for (int j = 0; j < KT; ++j) {
            v2f v;
            v.x = s0[j]      * PRESCALE;
            v.y = s0[KK + j] * PRESCALE;
            d[j] = v;
        }
    }
}

// ---- Kernel 2: main. grid (49 seg, 28 kc), block 256 (lane = bc).
// u read DIRECTLY (no transpose): thread t's 64 hw values are contiguous ->
// 16 dwordx4 loads off one base, imm offsets, zero per-load address math.
// rf staged in LDS (1792 B), broadcast ds_read_b64. Scalar Schraudolph.
__global__ __launch_bounds__(256) void rf_main(const float* __restrict__ u,
                                               const v2f* __restrict__ rfsP,
                                               float* __restrict__ part) {
    const int seg = blockIdx.x;            // 0..48
    const int kc  = blockIdx.y;            // 0..27
    const int t   = threadIdx.x;           // bc

    __shared__ v2f rf_lds[SPP * KT];       // 224 pairs = 1792 B
    if (t < SPP * KT)
        rf_lds[t] = rfsP[((size_t)kc * HP2 + seg * SPP) * KT + t];
    __syncthreads();

    const float4* ub = (const float4*)(u + (size_t)t * HW + seg * 64);

    float acc[KT][2];
    #pragma unroll
    for (int j = 0; j < KT; ++j) { acc[j][0] = 0.f; acc[j][1] = 0.f; }

    float4 uv[8];
    #pragma unroll
    for (int half = 0; half < 2; ++half) {
        #pragma unroll
        for (int i = 0; i < 8; ++i)
            uv[i] = ub[half * 8 + i];
        #pragma unroll
        for (int i = 0; i < 8; ++i) {
            const float4 q = uv[i];
            const v2f* rl = &rf_lds[(half * 16 + 2 * i) * KT];
            #pragma unroll
            for (int j = 0; j < KT; ++j) {
                const v2f ra = rl[j];
                const v2f rb = rl[KT + j];
                acc[j][0] += __int_as_float((int)fmaf(q.x, ra.x, SCH_BIAS));
                acc[j][1] += __int_as_float((int)fmaf(q.y, ra.y, SCH_BIAS));
                acc[j][0] += __int_as_float((int)fmaf(q.z, rb.x, SCH_BIAS));
                acc[j][1] += __int_as_float((int)fmaf(q.w, rb.y, SCH_BIAS));
            }
        }
    }

    float* pp = part + (size_t)(kc * NSEG + seg) * KT * BCN + t;
    #pragma unroll
    for (int j = 0; j < KT; ++j)
        pp[j * BCN] = acc[j][0] + acc[j][1];
}

// ---- Kernel 3: reduce 49 segments, p = S/(1+S). grid (196, 4) x 64 threads.
__global__ __launch_bounds__(64) void rf_fin(const float* __restrict__ part,
                                             float* __restrict__ out) {
    const int k  = blockIdx.x;                      // 0..195
    const int bc = blockIdx.y * 64 + threadIdx.x;   // 0..255
    const int kc = k / KT;
    const int j  = k % KT;
    const float* pb = part + ((size_t)kc * NSEG * KT + j) * BCN + bc;
    float s = 0.f;
    #pragma unroll 7
    for (int sg = 0; sg < NSEG; ++sg)
        s += pb[(size_t)sg * KT * BCN];
    out[(size_t)bc * KK + k] = s / (1.0f + s);
}

// ---- Fallback (no workspace): monolithic, lane = k. Known-correct path (real exp2).
__global__ __launch_bounds__(256) void rf_pool_fallback(const float* __restrict__ u,
                                                        const float* __restrict__ rfs,
                                                        float* __restrict__ out) {
    const int grp = blockIdx.x;
    const int tid = threadIdx.x;
    const int bc0 = grp * 8;
    __shared__ __align__(16) float u_lds[8][196];
    float sum[8];
    #pragma unroll
    for (int g = 0; g < 8; ++g) sum[g] = 0.0f;
    for (int base = 0; base < HW; base += 196) {
        __syncthreads();
        if (tid < 196) {
            #pragma unroll
            for (int g = 0; g < 8; ++g)
                u_lds[g][tid] = u[(bc0 + g) * HW + base + tid] * LOG2E;
        }
        __syncthreads();
        if (tid < KK) {
            const float* rp = rfs + (size_t)base * KK + tid;
            for (int h = 0; h < 196; h += 4) {
                float rf0 = rp[(h + 0) * KK];
                float rf1 = rp[(h + 1) * KK];
                float rf2 = rp[(h + 2) * KK];
                float rf3 = rp[(h + 3) * KK];
                #pragma unroll
                for (int g = 0; g < 8; ++g) {
                    float4 ug = *(const float4*)&u_lds[g][h];
                    sum[g] += __builtin_amdgcn_exp2f(ug.x * rf0);
                    sum[g] += __builtin_amdgcn_exp2f(ug.y * rf1);
                    sum[g] += __builtin_amdgcn_exp2f(ug.z * rf2);
                    sum[g] += __builtin_amdgcn_exp2f(ug.w * rf3);
                }
            }
        }
    }
    if (tid < KK) {
        #pragma unroll
        for (int g = 0; g < 8; ++g) {
            float s = sum[g];
            out[(size_t)(bc0 + g) * KK + tid] = s / (s + 1.0f);
        }
    }
}

extern "C" void kernel_launch(void* const* d_in, const int* in_sizes, int n_in,
                              void* d_out, int out_size, void* d_ws, size_t ws_size,
                              hipStream_t stream) {
    const float* u   = (const float*)d_in[0];   // (8,32,56,56) f32
    const float* rfs = (const float*)d_in[1];   // (56,56,196) f32
    float* out = (float*)d_out;                 // (8,32,196) f32

    const size_t rfsP_off = 0;                                   // 343 KB
    const size_t part_off = 1u << 20;                            // @1 MB, 9.83 MB
    const size_t need     = part_off + (size_t)NKC * NSEG * KT * BCN * sizeof(float);
    if (ws_size >= need) {
        v2f*   rfsP = (v2f*)((char*)d_ws + rfsP_off);
        float* part = (float*)((char*)d_ws + part_off);
        const int repack_blocks = (NKC * HP2 + 255) / 256;       // 172
        rf_repack<<<repack_blocks, 256, 0, stream>>>(rfs, rfsP);
        rf_main<<<dim3(NSEG, NKC), 256, 0, stream>>>(u, rfsP, part);
        rf_fin<<<dim3(KK, 4), 64, 0, stream>>>(part, out);
    } else {
        rf_pool_fallback<<<BCN / 8, 256, 0, stream>>>(u, rfs, out);
    }
}